// Round 11
// baseline (364.556 us; speedup 1.0000x reference)
//
#include <hip/hip_runtime.h>
#include <hip/hip_bf16.h>

#define IN_DIM   128
#define HIDDEN   256
#define OUT_DIM  128
#define N_NODES  100000
#define N_EDGES  500000
#define N_ROWS   (2 * N_EDGES)   // 1,000,000 rows (2 MC x edges)

typedef __bf16 bf16x8  __attribute__((ext_vector_type(8)));
typedef float  f32x16  __attribute__((ext_vector_type(16)));

// ws layout:
//   [0, 196608)           12 weight chunks x 16384 B (32 n-cols x 512 B, K=256
//                         bf16, XOR-swizzled by ((n&7)<<4) in 16B granules;
//                         chunks 0..7 = W1^T, 8..11 = W2^T)
//   [196608, +51200000)   xbf: x as bf16, row-major [2*N_NODES][128] (256 B rows)
#define W1S_OFF 0
#define W2S_OFF 131072
#define XBF_OFF 196608

__global__ void prep_weights(const float* __restrict__ W1,
                             const float* __restrict__ W2,
                             unsigned char* __restrict__ ws) {
  int t = blockIdx.x * 256 + threadIdx.x;
  if (t < HIDDEN * HIDDEN) {           // W1: [k=256][n=256] row-major input
    int n = t & 255, k = t >> 8;
    __bf16 b = (__bf16)W1[k * HIDDEN + n];
    int byte = W1S_OFF + n * 512 + ((k * 2) ^ ((n & 7) << 4));
    *reinterpret_cast<__bf16*>(ws + byte) = b;
  } else {
    int t2 = t - HIDDEN * HIDDEN;
    if (t2 < HIDDEN * OUT_DIM) {       // W2: [k=256][n=128]
      int n = t2 & 127, k = t2 >> 7;
      __bf16 b = (__bf16)W2[k * OUT_DIM + n];
      int byte = W2S_OFF + n * 512 + ((k * 2) ^ ((n & 7) << 4));
      *reinterpret_cast<__bf16*>(ws + byte) = b;
    }
  }
}

// x fp32 -> bf16 table (25.6M elements, 8 per thread, fully coalesced)
__global__ __launch_bounds__(256)
void prep_x(const float* __restrict__ x, unsigned char* __restrict__ xbf) {
  long i = ((long)blockIdx.x * 256 + threadIdx.x) * 8;
  float4 f0 = *reinterpret_cast<const float4*>(x + i);
  float4 f1 = *reinterpret_cast<const float4*>(x + i + 4);
  bf16x8 a;
  a[0] = (__bf16)f0.x; a[1] = (__bf16)f0.y; a[2] = (__bf16)f0.z; a[3] = (__bf16)f0.w;
  a[4] = (__bf16)f1.x; a[5] = (__bf16)f1.y; a[6] = (__bf16)f1.z; a[7] = (__bf16)f1.w;
  *reinterpret_cast<bf16x8*>(xbf + i * 2) = a;
}

static __device__ __forceinline__ unsigned pack_bf16(float a, float b) {
  __bf16 x = (__bf16)a, y = (__bf16)b;
  unsigned short ux = __builtin_bit_cast(unsigned short, x);
  unsigned short uy = __builtin_bit_cast(unsigned short, y);
  return (unsigned)ux | ((unsigned)uy << 16);
}

// relu + pack + register-transpose (bias already folded in via MFMA).
// C: col=edge=el, row m=(reg&3)+8*(reg>>2)+4*hi.
static __device__ __forceinline__ void h_pack_nb(const f32x16 acc,
                                                 bf16x8& oe, bf16x8& oo) {
  unsigned w0 = pack_bf16(fmaxf(acc[0], 0.f),  fmaxf(acc[1], 0.f));
  unsigned w1 = pack_bf16(fmaxf(acc[2], 0.f),  fmaxf(acc[3], 0.f));
  unsigned w2 = pack_bf16(fmaxf(acc[4], 0.f),  fmaxf(acc[5], 0.f));
  unsigned w3 = pack_bf16(fmaxf(acc[6], 0.f),  fmaxf(acc[7], 0.f));
  unsigned w4 = pack_bf16(fmaxf(acc[8], 0.f),  fmaxf(acc[9], 0.f));
  unsigned w5 = pack_bf16(fmaxf(acc[10], 0.f), fmaxf(acc[11], 0.f));
  unsigned w6 = pack_bf16(fmaxf(acc[12], 0.f), fmaxf(acc[13], 0.f));
  unsigned w7 = pack_bf16(fmaxf(acc[14], 0.f), fmaxf(acc[15], 0.f));
  // half-wave exchange: vdst' = (a.row0, b.row0); vsrc' = (a.row1, b.row1)
  asm("v_permlane32_swap_b32 %0, %1" : "+v"(w0), "+v"(w2));
  asm("v_permlane32_swap_b32 %0, %1" : "+v"(w1), "+v"(w3));
  asm("v_permlane32_swap_b32 %0, %1" : "+v"(w4), "+v"(w6));
  asm("v_permlane32_swap_b32 %0, %1" : "+v"(w5), "+v"(w7));
  uint4 fe; fe.x = w0; fe.y = w1; fe.z = w2; fe.w = w3;
  uint4 fo; fo.x = w4; fo.y = w5; fo.z = w6; fo.w = w7;
  oe = __builtin_bit_cast(bf16x8, fe);
  oo = __builtin_bit_cast(bf16x8, fo);
}

// 128 threads = 2 waves x 32 edges (proven R3/R6/R9/R10 compute structure).
// NEW (T3/T4): double-buffered 2x16KB weight chunks, COUNTED vmcnt (never 0)
// + raw s_barrier — staging loads for chunk t+1/t+2 stay in flight across
// barriers; no full VMEM drain anywhere in the loop (R2-R10 plateau: 24
// vmcnt(0) drains per block serialized stage/LDS/MFMA; cycles summed not
// overlapped). Biases folded in as one rank-1 MFMA per phase so the loop
// body has ZERO global loads (keeps vmcnt arithmetic exact). Memory-clobber
// asm fences pin VMEM program order (each wave waits its OWN 8 staging loads
// before the barrier; barrier then publishes both waves' halves).
// NOTE: do NOT use 256-thread variants — R5 miscompiled (absmax 1.75).
// NOTE: do NOT cap min-waves — R4 spilled ~900 MB (live set ~160 VGPR).
__global__ __launch_bounds__(128)
void edge_mlp(const int* __restrict__ eidx,
              const unsigned char* __restrict__ xbf,
              const float* __restrict__ b1,
              const float* __restrict__ b2,
              const unsigned char* __restrict__ ws,
              float* __restrict__ out) {
  __shared__ __align__(16) unsigned char wbuf[2][16384];

  const int tid  = threadIdx.x;
  const int wv   = tid >> 6;           // wave 0..1
  const int lane = tid & 63;
  const int el   = lane & 31;          // edge within wave tile
  const int hi   = lane >> 5;          // k half

  const long base = (long)blockIdx.x * 64;
  const long gr   = base + wv * 32 + el;
  const int  mc   = (gr >= N_EDGES) ? 1 : 0;
  const int  e    = (int)(gr - (long)mc * N_EDGES);
  const int  sn   = eidx[e];
  const int  dn   = eidx[N_EDGES + e];
  const unsigned char* xsb = xbf + ((long)mc * N_NODES + sn) * 256;
  const unsigned char* xdb = xbf + ((long)mc * N_NODES + dn) * 256;

  // ---- prologue loads: per-lane bias values + x fragments ----
  float b1v[8], b2v[4];
#pragma unroll
  for (int c = 0; c < 8; ++c) b1v[c] = b1[c * 32 + el];
#pragma unroll
  for (int c = 0; c < 4; ++c) b2v[c] = b2[c * 32 + el];

  // x fragments (B of swapped L1, 32x32x16): lane holds edge=el,
  // k = s*16 + hi*8 + j -> bf16 row byte s*32 + hi*16, 16 B direct
  bf16x8 a1[16];
#pragma unroll
  for (int s = 0; s < 16; ++s) {
    const unsigned char* p = (s < 8) ? (xsb + s * 32 + hi * 16)
                                     : (xdb + (s - 8) * 32 + hi * 16);
    a1[s] = *reinterpret_cast<const bf16x8*>(p);
  }
  asm volatile("" ::: "memory");       // pin: gathers/bias before staging

  // one 16 KB chunk -> dbuf slot b; 8 sweeps of 2048 B (8 loads per wave)
#define STAGE(t, b)                                                            \
  do {                                                                         \
    const unsigned char* g_ = ws + (t) * 16384;                                \
    _Pragma("unroll")                                                          \
    for (int i_ = 0; i_ < 8; ++i_) {                                           \
      __builtin_amdgcn_global_load_lds(                                        \
          (const __attribute__((address_space(1))) unsigned int*)(g_ + i_ * 2048 + tid * 16), \
          (__attribute__((address_space(3))) unsigned int*)(&wbuf[b][i_ * 2048 + tid * 16]),  \
          16, 0, 0);                                                           \
    }                                                                          \
  } while (0)

  STAGE(0, 0);
  asm volatile("" ::: "memory");       // pin: S0 older than S1
  STAGE(1, 1);
  asm volatile("" ::: "memory");

  bf16x8 onefrag = {};                 // A/B "ones at k'=0" fragment
  if (hi == 0) onefrag[0] = (__bf16)1.0f;

  const int rowb = el * 512;
  const int swz  = (el & 7) << 4;
  bf16x8 a2[16];

  // ---- 12 phases, counted-vmcnt pipeline ----
#pragma unroll
  for (int t = 0; t < 12; ++t) {
    // wait until chunk t's 8 staging loads (this wave's share) have landed;
    // later chunks' loads stay in flight. Stores enter the count at t>=9.
    if (t <= 8)       asm volatile("s_waitcnt vmcnt(8)"  ::: "memory");
    else if (t <= 10) asm volatile("s_waitcnt vmcnt(24)" ::: "memory");
    else              asm volatile("s_waitcnt vmcnt(16)" ::: "memory");
    __builtin_amdgcn_s_barrier();      // publish both waves' halves
    asm volatile("" ::: "memory");

    if (t < 8) {
      // layer 1 (swapped): D[hcol][edge] = W1^T x  (+ bias via rank-1 MFMA)
      f32x16 aE = {}, aO = {};
      bf16x8 bfr = {};
      if (hi == 0) bfr[0] = (__bf16)b1v[t];
      aE = __builtin_amdgcn_mfma_f32_32x32x16_bf16(bfr, onefrag, aE, 0, 0, 0);
#pragma unroll
      for (int ks = 0; ks < 8; ++ks) {
        const int offE = rowb + (((2 * ks) * 32 + hi * 16) ^ swz);
        const int offO = rowb + (((2 * ks + 1) * 32 + hi * 16) ^ swz);
        bf16x8 wE = *reinterpret_cast<const bf16x8*>(&wbuf[t & 1][offE]);
        bf16x8 wO = *reinterpret_cast<const bf16x8*>(&wbuf[t & 1][offO]);
        aE = __builtin_amdgcn_mfma_f32_32x32x16_bf16(wE, a1[2 * ks],     aE, 0, 0, 0);
        aO = __builtin_amdgcn_mfma_f32_32x32x16_bf16(wO, a1[2 * ks + 1], aO, 0, 0, 0);
      }
      f32x16 acc = aE + aO;
      h_pack_nb(acc, a2[2 * t], a2[2 * t + 1]);
    } else {
      // layer 2 (standard): out[edge][ocol] = h W2 (+ bias via rank-1 MFMA)
      const int u = t - 8;
      f32x16 aE = {}, aO = {};
      bf16x8 bfr = {};
      if (hi == 0) bfr[0] = (__bf16)b2v[u];
      aE = __builtin_amdgcn_mfma_f32_32x32x16_bf16(onefrag, bfr, aE, 0, 0, 0);
#pragma unroll
      for (int ks = 0; ks < 8; ++ks) {
        const int offE = rowb + (((2 * ks) * 32 + hi * 16) ^ swz);
        const int offO = rowb + (((2 * ks + 1) * 32 + hi * 16) ^ swz);
        bf16x8 wE = *reinterpret_cast<const bf16x8*>(&wbuf[t & 1][offE]);
        bf16x8 wO = *reinterpret_cast<const bf16x8*>(&wbuf[t & 1][offO]);
        aE = __builtin_amdgcn_mfma_f32_32x32x16_bf16(a2[2 * ks],     wE, aE, 0, 0, 0);
        aO = __builtin_amdgcn_mfma_f32_32x32x16_bf16(a2[2 * ks + 1], wO, aO, 0, 0, 0);
      }
      f32x16 acc = aE + aO;
      const long r0 = base + wv * 32;
#pragma unroll
      for (int reg = 0; reg < 16; ++reg) {
        int m = (reg & 3) + 8 * (reg >> 2) + 4 * hi;
        out[(r0 + m) * OUT_DIM + u * 32 + el] = acc[reg];
      }
    }

    asm volatile("" ::: "memory");
    __builtin_amdgcn_s_barrier();      // all waves done reading buf[t&1]
    asm volatile("" ::: "memory");
    if (t + 2 < 12) STAGE(t + 2, t & 1);
  }
#undef STAGE
}

extern "C" void kernel_launch(void* const* d_in, const int* in_sizes, int n_in,
                              void* d_out, int out_size, void* d_ws, size_t ws_size,
                              hipStream_t stream) {
  const int*   eidx = (const int*)d_in[0];
  const float* x    = (const float*)d_in[1];
  const float* b1   = (const float*)d_in[3];
  const float* b2   = (const float*)d_in[5];
  float* out = (float*)d_out;
  unsigned char* ws = (unsigned char*)d_ws;

  prep_weights<<<(HIDDEN * HIDDEN + HIDDEN * OUT_DIM) / 256, 256, 0, stream>>>(
      (const float*)d_in[2], (const float*)d_in[4], ws);

  // x -> bf16 table: 25.6M elements, 8/thread -> 12500 blocks exactly
  prep_x<<<12500, 256, 0, stream>>>(x, ws + XBF_OFF);

  // 64 rows per block, exact grid (no tail)
  edge_mlp<<<N_ROWS / 64, 128, 0, stream>>>(eidx, ws + XBF_OFF, b1, b2, ws, out);
  (void)in_sizes; (void)n_in; (void)out_size; (void)ws_size;
}

// Round 12
// 359.731 us; speedup vs baseline: 1.0134x; 1.0134x over previous
//
#include <hip/hip_runtime.h>
#include <hip/hip_bf16.h>

#define IN_DIM   128
#define HIDDEN   256
#define OUT_DIM  128
#define N_NODES  100000
#define N_EDGES  500000
#define N_ROWS   (2 * N_EDGES)   // 1,000,000 rows (2 MC x edges)

typedef __bf16 bf16x8  __attribute__((ext_vector_type(8)));
typedef float  f32x16  __attribute__((ext_vector_type(16)));

// ws layout:
//   [0, 196608)           12 weight chunks x 16384 B (32 n-cols x 512 B, K=256
//                         bf16, XOR-swizzled by ((n&7)<<4) in 16B granules;
//                         chunks 0..7 = W1^T, 8..11 = W2^T)
//   [196608, +51200000)   xbf: x as bf16, row-major [2*N_NODES][128] (256 B rows)
#define W1S_OFF 0
#define W2S_OFF 131072
#define XBF_OFF 196608

__global__ void prep_weights(const float* __restrict__ W1,
                             const float* __restrict__ W2,
                             unsigned char* __restrict__ ws) {
  int t = blockIdx.x * 256 + threadIdx.x;
  if (t < HIDDEN * HIDDEN) {           // W1: [k=256][n=256] row-major input
    int n = t & 255, k = t >> 8;
    __bf16 b = (__bf16)W1[k * HIDDEN + n];
    int byte = W1S_OFF + n * 512 + ((k * 2) ^ ((n & 7) << 4));
    *reinterpret_cast<__bf16*>(ws + byte) = b;
  } else {
    int t2 = t - HIDDEN * HIDDEN;
    if (t2 < HIDDEN * OUT_DIM) {       // W2: [k=256][n=128]
      int n = t2 & 127, k = t2 >> 7;
      __bf16 b = (__bf16)W2[k * OUT_DIM + n];
      int byte = W2S_OFF + n * 512 + ((k * 2) ^ ((n & 7) << 4));
      *reinterpret_cast<__bf16*>(ws + byte) = b;
    }
  }
}

// x fp32 -> bf16 table (25.6M elements, 8 per thread, fully coalesced)
__global__ __launch_bounds__(256)
void prep_x(const float* __restrict__ x, unsigned char* __restrict__ xbf) {
  long i = ((long)blockIdx.x * 256 + threadIdx.x) * 8;
  float4 f0 = *reinterpret_cast<const float4*>(x + i);
  float4 f1 = *reinterpret_cast<const float4*>(x + i + 4);
  bf16x8 a;
  a[0] = (__bf16)f0.x; a[1] = (__bf16)f0.y; a[2] = (__bf16)f0.z; a[3] = (__bf16)f0.w;
  a[4] = (__bf16)f1.x; a[5] = (__bf16)f1.y; a[6] = (__bf16)f1.z; a[7] = (__bf16)f1.w;
  *reinterpret_cast<bf16x8*>(xbf + i * 2) = a;
}

static __device__ __forceinline__ unsigned pack_bf16(float a, float b) {
  __bf16 x = (__bf16)a, y = (__bf16)b;
  unsigned short ux = __builtin_bit_cast(unsigned short, x);
  unsigned short uy = __builtin_bit_cast(unsigned short, y);
  return (unsigned)ux | ((unsigned)uy << 16);
}

// L1 epilogue: bias+relu+pack+register-transpose (proven R3/R6/R9/R10).
// C: col=edge=el, row m=(reg&3)+8*(reg>>2)+4*hi.
static __device__ __forceinline__ void h_pack(const f32x16 acc,
                                              const float* __restrict__ b1c,
                                              int hi, bf16x8& oe, bf16x8& oo) {
  float4 bv0 = *reinterpret_cast<const float4*>(b1c + hi * 4);
  float4 bv1 = *reinterpret_cast<const float4*>(b1c + 8 + hi * 4);
  float4 bv2 = *reinterpret_cast<const float4*>(b1c + 16 + hi * 4);
  float4 bv3 = *reinterpret_cast<const float4*>(b1c + 24 + hi * 4);
  unsigned w0 = pack_bf16(fmaxf(acc[0] + bv0.x, 0.f),  fmaxf(acc[1] + bv0.y, 0.f));
  unsigned w1 = pack_bf16(fmaxf(acc[2] + bv0.z, 0.f),  fmaxf(acc[3] + bv0.w, 0.f));
  unsigned w2 = pack_bf16(fmaxf(acc[4] + bv1.x, 0.f),  fmaxf(acc[5] + bv1.y, 0.f));
  unsigned w3 = pack_bf16(fmaxf(acc[6] + bv1.z, 0.f),  fmaxf(acc[7] + bv1.w, 0.f));
  unsigned w4 = pack_bf16(fmaxf(acc[8] + bv2.x, 0.f),  fmaxf(acc[9] + bv2.y, 0.f));
  unsigned w5 = pack_bf16(fmaxf(acc[10] + bv2.z, 0.f), fmaxf(acc[11] + bv2.w, 0.f));
  unsigned w6 = pack_bf16(fmaxf(acc[12] + bv3.x, 0.f), fmaxf(acc[13] + bv3.y, 0.f));
  unsigned w7 = pack_bf16(fmaxf(acc[14] + bv3.z, 0.f), fmaxf(acc[15] + bv3.w, 0.f));
  // half-wave exchange: vdst' = (a.row0, b.row0); vsrc' = (a.row1, b.row1)
  asm("v_permlane32_swap_b32 %0, %1" : "+v"(w0), "+v"(w2));
  asm("v_permlane32_swap_b32 %0, %1" : "+v"(w1), "+v"(w3));
  asm("v_permlane32_swap_b32 %0, %1" : "+v"(w4), "+v"(w6));
  asm("v_permlane32_swap_b32 %0, %1" : "+v"(w5), "+v"(w7));
  uint4 fe; fe.x = w0; fe.y = w1; fe.z = w2; fe.w = w3;
  uint4 fo; fo.x = w4; fo.y = w5; fo.z = w6; fo.w = w7;
  oe = __builtin_bit_cast(bf16x8, fe);
  oo = __builtin_bit_cast(bf16x8, fo);
}

// GEOMETRY CHANGE (R12): one 512-thread block = 8 waves x 32 edges = 256 edges.
// Weights staged in 3 windows of 64 KB (4 chunks); between the 6 total
// __syncthreads the 8 waves FREE-RUN (no per-phase convoy — R2-R11's 2-wave
// 12-phase blocks summed pipe times; LDS-read serial-equivalent ~170us was
// the geometry floor). Compute internals byte-identical R10 (a1 gather from
// bf16 table, E/O dual MFMA chains, h_pack permlane transpose, swizzled LDS
// reads). Tail: grid 3907, last block has 2 valid waves (wave-uniform guard,
// clamped gather — proven R4). Plain __syncthreads only; no prefetch races.
// NOTE: do NOT cap min-waves — R4 spilled ~900 MB (live set ~190 VGPR).
__global__ __launch_bounds__(512)
void edge_mlp(const int* __restrict__ eidx,
              const unsigned char* __restrict__ xbf,
              const float* __restrict__ b1,
              const float* __restrict__ b2,
              const unsigned char* __restrict__ ws,
              float* __restrict__ out) {
  __shared__ __align__(16) unsigned char wl[65536];   // 4-chunk window

  const int tid  = threadIdx.x;
  const int wv   = tid >> 6;           // wave 0..7
  const int lane = tid & 63;
  const int el   = lane & 31;          // edge within wave tile
  const int hi   = lane >> 5;          // k half

  const long base = (long)blockIdx.x * 256;
  const long row0 = base + wv * 32;
  const bool wvalid = row0 < N_ROWS;                  // wave-uniform
  const long gr   = row0 + el;
  const long grc  = (gr < N_ROWS) ? gr : (N_ROWS - 1);
  const int  mc   = (grc >= N_EDGES) ? 1 : 0;
  const int  e    = (int)(grc - (long)mc * N_EDGES);
  const int  sn   = eidx[e];
  const int  dn   = eidx[N_EDGES + e];
  const unsigned char* xsb = xbf + ((long)mc * N_NODES + sn) * 256;
  const unsigned char* xdb = xbf + ((long)mc * N_NODES + dn) * 256;

  // ---- x fragments (B of swapped L1, 32x32x16): lane holds edge=el,
  //      k = s*16 + hi*8 + j -> bf16 row byte s*32 + hi*16, 16 B direct ----
  bf16x8 a1[16];
#pragma unroll
  for (int s = 0; s < 16; ++s) {
    const unsigned char* p = (s < 8) ? (xsb + s * 32 + hi * 16)
                                     : (xdb + (s - 8) * 32 + hi * 16);
    a1[s] = *reinterpret_cast<const bf16x8*>(p);
  }

  // 512 threads copy one 64 KB window (4 chunks) in 8 sweeps of 8192 B
#define STAGE4(t0)                                                             \
  do {                                                                         \
    const unsigned char* g_ = ws + (t0) * 16384;                               \
    _Pragma("unroll")                                                          \
    for (int i_ = 0; i_ < 8; ++i_) {                                           \
      __builtin_amdgcn_global_load_lds(                                        \
          (const __attribute__((address_space(1))) unsigned int*)(g_ + i_ * 8192 + tid * 16), \
          (__attribute__((address_space(3))) unsigned int*)(&wl[i_ * 8192 + tid * 16]),       \
          16, 0, 0);                                                           \
    }                                                                          \
  } while (0)

  const int rowb = el * 512;
  const int swz  = (el & 7) << 4;
  bf16x8 a2[16];

  // ---- layer 1 (swapped): D[hcol][edge] = W1^T x, two 4-chunk windows ----
#pragma unroll
  for (int w = 0; w < 2; ++w) {
    if (w) __syncthreads();            // all waves done with window 0
    STAGE4(w * 4);
    __syncthreads();                   // window staged (drain + barrier)
#pragma unroll
    for (int cl = 0; cl < 4; ++cl) {   // free-run: no syncs inside
      const int cc = w * 4 + cl;
      const unsigned char* cb = wl + cl * 16384;
      f32x16 aE = {}, aO = {};
#pragma unroll
      for (int ks = 0; ks < 8; ++ks) {
        const int offE = rowb + (((2 * ks) * 32 + hi * 16) ^ swz);
        const int offO = rowb + (((2 * ks + 1) * 32 + hi * 16) ^ swz);
        bf16x8 wE = *reinterpret_cast<const bf16x8*>(cb + offE);
        bf16x8 wO = *reinterpret_cast<const bf16x8*>(cb + offO);
        aE = __builtin_amdgcn_mfma_f32_32x32x16_bf16(wE, a1[2 * ks],     aE, 0, 0, 0);
        aO = __builtin_amdgcn_mfma_f32_32x32x16_bf16(wO, a1[2 * ks + 1], aO, 0, 0, 0);
      }
      f32x16 acc = aE + aO;
      h_pack(acc, b1 + cc * 32, hi, a2[2 * cc], a2[2 * cc + 1]);
    }
  }

  // ---- layer 2 (standard): out[edge][ocol] = h W2 + b2 ----
  __syncthreads();                     // all waves done with window 1
  STAGE4(8);                           // W2 chunks 8..11
  __syncthreads();
#pragma unroll
  for (int oc = 0; oc < 4; ++oc) {     // free-run + stores
    const unsigned char* cb = wl + oc * 16384;
    f32x16 aE = {}, aO = {};
#pragma unroll
    for (int ks = 0; ks < 8; ++ks) {
      const int offE = rowb + (((2 * ks) * 32 + hi * 16) ^ swz);
      const int offO = rowb + (((2 * ks + 1) * 32 + hi * 16) ^ swz);
      bf16x8 wE = *reinterpret_cast<const bf16x8*>(cb + offE);
      bf16x8 wO = *reinterpret_cast<const bf16x8*>(cb + offO);
      aE = __builtin_amdgcn_mfma_f32_32x32x16_bf16(a2[2 * ks],     wE, aE, 0, 0, 0);
      aO = __builtin_amdgcn_mfma_f32_32x32x16_bf16(a2[2 * ks + 1], wO, aO, 0, 0, 0);
    }
    if (wvalid) {
      f32x16 acc = aE + aO;
      float bvo = b2[oc * 32 + el];
      const long r0 = base + wv * 32;
#pragma unroll
      for (int reg = 0; reg < 16; ++reg) {
        int m = (reg & 3) + 8 * (reg >> 2) + 4 * hi;
        out[(r0 + m) * OUT_DIM + oc * 32 + el] = acc[reg] + bvo;
      }
    }
  }
#undef STAGE4
}

extern "C" void kernel_launch(void* const* d_in, const int* in_sizes, int n_in,
                              void* d_out, int out_size, void* d_ws, size_t ws_size,
                              hipStream_t stream) {
  const int*   eidx = (const int*)d_in[0];
  const float* x    = (const float*)d_in[1];
  const float* b1   = (const float*)d_in[3];
  const float* b2   = (const float*)d_in[5];
  float* out = (float*)d_out;
  unsigned char* ws = (unsigned char*)d_ws;

  prep_weights<<<(HIDDEN * HIDDEN + HIDDEN * OUT_DIM) / 256, 256, 0, stream>>>(
      (const float*)d_in[2], (const float*)d_in[4], ws);

  // x -> bf16 table: 25.6M elements, 8/thread -> 12500 blocks exactly
  prep_x<<<12500, 256, 0, stream>>>(x, ws + XBF_OFF);

  // 256 rows per block; grid 3907 (tail block: 2 valid waves, wave-uniform)
  edge_mlp<<<(N_ROWS + 255) / 256, 512, 0, stream>>>(eidx, ws + XBF_OFF, b1, b2, ws, out);
  (void)in_sizes; (void)n_in; (void)out_size; (void)ws_size;
}

// Round 13
// 341.847 us; speedup vs baseline: 1.0664x; 1.0523x over previous
//
#include <hip/hip_runtime.h>
#include <hip/hip_bf16.h>

#define IN_DIM   128
#define HIDDEN   256
#define OUT_DIM  128
#define N_NODES  100000
#define N_EDGES  500000
#define N_ROWS   (2 * N_EDGES)   // 1,000,000 rows (2 MC x edges)

typedef __bf16 bf16x8  __attribute__((ext_vector_type(8)));
typedef float  f32x16  __attribute__((ext_vector_type(16)));

// ws layout:
//   [0, 196608)           12 weight chunks x 16384 B, GRANULE-MAJOR:
//                         chunk = 32 output-cols (n) x 256 k; fragment
//                         (k-granule g = k>>3, n) stored at g*512 + n*16
//                         (+ (k&7)*2 within the 16 B granule).
//                         A wave's ds_read_b128 of frag(s,hi) then hits
//                         s*1024 + hi*512 + el*16: each 32-lane half reads
//                         512 CONSECUTIVE bytes -> zero bank conflicts
//                         (old [n][k] layout: every row started at bank 0,
//                         3-bit XOR swizzle left 4-way conflicts = 2.4e7
//                         extra cycles). Chunks 0..7 = W1^T, 8..11 = W2^T.
//   [196608, +51200000)   xbf: x as bf16, row-major [2*N_NODES][128] (256 B rows)
#define XBF_OFF 196608

__global__ void prep_weights(const float* __restrict__ W1,
                             const float* __restrict__ W2,
                             unsigned char* __restrict__ ws) {
  int t = blockIdx.x * 256 + threadIdx.x;
  if (t < HIDDEN * HIDDEN) {           // W1: [k=256][n=256] row-major input
    int n = t & 255, k = t >> 8;
    __bf16 b = (__bf16)W1[k * HIDDEN + n];
    int byte = (n >> 5) * 16384 + (k >> 3) * 512 + (n & 31) * 16 + (k & 7) * 2;
    *reinterpret_cast<__bf16*>(ws + byte) = b;
  } else {
    int t2 = t - HIDDEN * HIDDEN;
    if (t2 < HIDDEN * OUT_DIM) {       // W2: [k=256][n=128]
      int n = t2 & 127, k = t2 >> 7;
      __bf16 b = (__bf16)W2[k * OUT_DIM + n];
      int byte = (8 + (n >> 5)) * 16384 + (k >> 3) * 512 + (n & 31) * 16 + (k & 7) * 2;
      *reinterpret_cast<__bf16*>(ws + byte) = b;
    }
  }
}

// x fp32 -> bf16 table (25.6M elements, 8 per thread, fully coalesced)
__global__ __launch_bounds__(256)
void prep_x(const float* __restrict__ x, unsigned char* __restrict__ xbf) {
  long i = ((long)blockIdx.x * 256 + threadIdx.x) * 8;
  float4 f0 = *reinterpret_cast<const float4*>(x + i);
  float4 f1 = *reinterpret_cast<const float4*>(x + i + 4);
  bf16x8 a;
  a[0] = (__bf16)f0.x; a[1] = (__bf16)f0.y; a[2] = (__bf16)f0.z; a[3] = (__bf16)f0.w;
  a[4] = (__bf16)f1.x; a[5] = (__bf16)f1.y; a[6] = (__bf16)f1.z; a[7] = (__bf16)f1.w;
  *reinterpret_cast<bf16x8*>(xbf + i * 2) = a;
}

static __device__ __forceinline__ unsigned pack_bf16(float a, float b) {
  __bf16 x = (__bf16)a, y = (__bf16)b;
  unsigned short ux = __builtin_bit_cast(unsigned short, x);
  unsigned short uy = __builtin_bit_cast(unsigned short, y);
  return (unsigned)ux | ((unsigned)uy << 16);
}

// L1 epilogue: bias+relu+pack+register-transpose (proven R3/R6/R9/R10).
// C: col=edge=el, row m=(reg&3)+8*(reg>>2)+4*hi.
static __device__ __forceinline__ void h_pack(const f32x16 acc,
                                              const float* __restrict__ b1c,
                                              int hi, bf16x8& oe, bf16x8& oo) {
  float4 bv0 = *reinterpret_cast<const float4*>(b1c + hi * 4);
  float4 bv1 = *reinterpret_cast<const float4*>(b1c + 8 + hi * 4);
  float4 bv2 = *reinterpret_cast<const float4*>(b1c + 16 + hi * 4);
  float4 bv3 = *reinterpret_cast<const float4*>(b1c + 24 + hi * 4);
  unsigned w0 = pack_bf16(fmaxf(acc[0] + bv0.x, 0.f),  fmaxf(acc[1] + bv0.y, 0.f));
  unsigned w1 = pack_bf16(fmaxf(acc[2] + bv0.z, 0.f),  fmaxf(acc[3] + bv0.w, 0.f));
  unsigned w2 = pack_bf16(fmaxf(acc[4] + bv1.x, 0.f),  fmaxf(acc[5] + bv1.y, 0.f));
  unsigned w3 = pack_bf16(fmaxf(acc[6] + bv1.z, 0.f),  fmaxf(acc[7] + bv1.w, 0.f));
  unsigned w4 = pack_bf16(fmaxf(acc[8] + bv2.x, 0.f),  fmaxf(acc[9] + bv2.y, 0.f));
  unsigned w5 = pack_bf16(fmaxf(acc[10] + bv2.z, 0.f), fmaxf(acc[11] + bv2.w, 0.f));
  unsigned w6 = pack_bf16(fmaxf(acc[12] + bv3.x, 0.f), fmaxf(acc[13] + bv3.y, 0.f));
  unsigned w7 = pack_bf16(fmaxf(acc[14] + bv3.z, 0.f), fmaxf(acc[15] + bv3.w, 0.f));
  // half-wave exchange: vdst' = (a.row0, b.row0); vsrc' = (a.row1, b.row1)
  asm("v_permlane32_swap_b32 %0, %1" : "+v"(w0), "+v"(w2));
  asm("v_permlane32_swap_b32 %0, %1" : "+v"(w1), "+v"(w3));
  asm("v_permlane32_swap_b32 %0, %1" : "+v"(w4), "+v"(w6));
  asm("v_permlane32_swap_b32 %0, %1" : "+v"(w5), "+v"(w7));
  uint4 fe; fe.x = w0; fe.y = w1; fe.z = w2; fe.w = w3;
  uint4 fo; fo.x = w4; fo.y = w5; fo.z = w6; fo.w = w7;
  oe = __builtin_bit_cast(bf16x8, fe);
  oo = __builtin_bit_cast(bf16x8, fo);
}

// R10 structure EXACTLY (best measured: 326 us) with one change: granule-major
// weight layout -> conflict-free ds_read_b128 (consecutive 16 B per lane) and
// XOR-free addressing (single base + compile-time offsets).
// 128 threads = 2 waves x 32 edges; 6 phases of 2 chunks, single 32 KB buffer,
// plain __syncthreads pairs; a1 gathered direct from the bf16 x-table (16 B
// fragments, zero conversion VALU); E/O dual MFMA chains; h_pack permlane
// transpose; coalesced stores.
// NOTE: do NOT use 256-thread variants — R5 miscompiled (absmax 1.75).
// NOTE: do NOT cap min-waves — R4 spilled ~900 MB (live set ~160+ VGPR).
__global__ __launch_bounds__(128)
void edge_mlp(const int* __restrict__ eidx,
              const unsigned char* __restrict__ xbf,
              const float* __restrict__ b1,
              const float* __restrict__ b2,
              const unsigned char* __restrict__ ws,
              float* __restrict__ out) {
  __shared__ __align__(16) unsigned char wbuf[32768];   // 2 chunks

  const int tid  = threadIdx.x;
  const int wv   = tid >> 6;           // wave 0..1
  const int lane = tid & 63;
  const int el   = lane & 31;          // edge within wave tile
  const int hi   = lane >> 5;          // k half

  const long base = (long)blockIdx.x * 64;
  const long gr   = base + wv * 32 + el;
  const int  mc   = (gr >= N_EDGES) ? 1 : 0;
  const int  e    = (int)(gr - (long)mc * N_EDGES);
  const int  sn   = eidx[e];
  const int  dn   = eidx[N_EDGES + e];
  const unsigned char* xsb = xbf + ((long)mc * N_NODES + sn) * 256;
  const unsigned char* xdb = xbf + ((long)mc * N_NODES + dn) * 256;

  // ---- x fragments (B of swapped L1, 32x32x16): lane holds edge=el,
  //      k = s*16 + hi*8 + j -> bf16 row byte s*32 + hi*16, 16 B direct ----
  bf16x8 a1[16];
#pragma unroll
  for (int s = 0; s < 16; ++s) {
    const unsigned char* p = (s < 8) ? (xsb + s * 32 + hi * 16)
                                     : (xdb + (s - 8) * 32 + hi * 16);
    a1[s] = *reinterpret_cast<const bf16x8*>(p);
  }

  // 128 threads copy TWO chunks (32768 B) in 16 sweeps of 2048 B
#define STAGE2(t)                                                              \
  do {                                                                         \
    const unsigned char* g_ = ws + (t) * 16384;                                \
    _Pragma("unroll")                                                          \
    for (int i_ = 0; i_ < 16; ++i_) {                                          \
      __builtin_amdgcn_global_load_lds(                                        \
          (const __attribute__((address_space(1))) unsigned int*)(g_ + i_ * 2048 + tid * 16), \
          (__attribute__((address_space(3))) unsigned int*)(&wbuf[i_ * 2048 + tid * 16]),     \
          16, 0, 0);                                                           \
    }                                                                          \
  } while (0)

  // per-lane weight-fragment base: frag(s,hi) of chunk c at
  //   c*16384 + s*1024 + hi*512 + el*16   (conflict-free: 32 lanes x 16 B
  //   consecutive per half-wave)
  const unsigned char* wb = wbuf + hi * 512 + el * 16;

  bf16x8 a2[16];

  // ---- layer 1 (swapped): 4 phases x 2 chunks; D[hcol][edge] = W1^T x ----
#pragma unroll
  for (int p = 0; p < 4; ++p) {
    const int c0 = 2 * p;
    __syncthreads();                    // previous phase's readers done
    STAGE2(c0);
    __syncthreads();                    // stage drained (vmcnt0 + barrier)
    f32x16 aA = {}, aB = {};
#pragma unroll
    for (int ks = 0; ks < 16; ++ks) {
      bf16x8 wfA = *reinterpret_cast<const bf16x8*>(wb + ks * 1024);
      bf16x8 wfB = *reinterpret_cast<const bf16x8*>(wb + 16384 + ks * 1024);
      aA = __builtin_amdgcn_mfma_f32_32x32x16_bf16(wfA, a1[ks], aA, 0, 0, 0);
      aB = __builtin_amdgcn_mfma_f32_32x32x16_bf16(wfB, a1[ks], aB, 0, 0, 0);
    }
    h_pack(aA, b1 + c0 * 32,      hi, a2[2 * c0],     a2[2 * c0 + 1]);
    h_pack(aB, b1 + c0 * 32 + 32, hi, a2[2 * c0 + 2], a2[2 * c0 + 3]);
  }

  // ---- layer 2 (standard): 2 phases x 2 chunks; out = h @ W2 + b2 ----
#pragma unroll
  for (int q = 0; q < 2; ++q) {
    const int oc0 = 2 * q;
    __syncthreads();
    STAGE2(8 + oc0);
    __syncthreads();
    f32x16 aA = {}, aB = {};
#pragma unroll
    for (int kk = 0; kk < 16; ++kk) {
      bf16x8 wfA = *reinterpret_cast<const bf16x8*>(wb + kk * 1024);
      bf16x8 wfB = *reinterpret_cast<const bf16x8*>(wb + 16384 + kk * 1024);
      aA = __builtin_amdgcn_mfma_f32_32x32x16_bf16(a2[kk], wfA, aA, 0, 0, 0);
      aB = __builtin_amdgcn_mfma_f32_32x32x16_bf16(a2[kk], wfB, aB, 0, 0, 0);
    }
    const long r0 = base + wv * 32;
    float bvA = b2[oc0 * 32 + el];
    float bvB = b2[oc0 * 32 + 32 + el];
#pragma unroll
    for (int reg = 0; reg < 16; ++reg) {
      int m = (reg & 3) + 8 * (reg >> 2) + 4 * hi;
      out[(r0 + m) * OUT_DIM + oc0 * 32 + el]      = aA[reg] + bvA;
      out[(r0 + m) * OUT_DIM + oc0 * 32 + 32 + el] = aB[reg] + bvB;
    }
  }
#undef STAGE2
}

extern "C" void kernel_launch(void* const* d_in, const int* in_sizes, int n_in,
                              void* d_out, int out_size, void* d_ws, size_t ws_size,
                              hipStream_t stream) {
  const int*   eidx = (const int*)d_in[0];
  const float* x    = (const float*)d_in[1];
  const float* b1   = (const float*)d_in[3];
  const float* b2   = (const float*)d_in[5];
  float* out = (float*)d_out;
  unsigned char* ws = (unsigned char*)d_ws;

  prep_weights<<<(HIDDEN * HIDDEN + HIDDEN * OUT_DIM) / 256, 256, 0, stream>>>(
      (const float*)d_in[2], (const float*)d_in[4], ws);

  // x -> bf16 table: 25.6M elements, 8/thread -> 12500 blocks exactly
  prep_x<<<12500, 256, 0, stream>>>(x, ws + XBF_OFF);

  // 64 rows per block, exact grid (no tail)
  edge_mlp<<<N_ROWS / 64, 128, 0, stream>>>(eidx, ws + XBF_OFF, b1, b2, ws, out);
  (void)in_sizes; (void)n_in; (void)out_size; (void)ws_size;
}